// Round 1
// baseline (259.361 us; speedup 1.0000x reference)
//
#include <hip/hip_runtime.h>

#define T_IN   1048576
#define T_OUT  1048564              // T_IN - 12
#define ROWS   32                   // 8 * 4
#define QUADS_PER_ROW (T_OUT / 4)   // 262141
#define TOTAL_QUADS (ROWS * QUADS_PER_ROW)

__global__ __launch_bounds__(256) void pinn_fused_conv13(
    const float* __restrict__ x,
    const float* __restrict__ fd,     // 5 taps (already scaled by 1/h^2)
    const float* __restrict__ gs,     // 9 taps
    float* __restrict__ out)
{
    // Compose the two correlations into one 13-tap kernel:
    // out[t] = sum_j gs[j] * sum_i fd[i] * x[t+i+j] = sum_k c[k]*x[t+k],
    // c[k] = sum_{i+j=k} fd[i]*gs[j].
    float f[5], g[9], c[13];
#pragma unroll
    for (int k = 0; k < 13; ++k) c[k] = 0.0f;
#pragma unroll
    for (int i = 0; i < 5; ++i) f[i] = fd[i];
#pragma unroll
    for (int j = 0; j < 9; ++j) g[j] = gs[j];
#pragma unroll
    for (int i = 0; i < 5; ++i)
#pragma unroll
        for (int j = 0; j < 9; ++j) c[i + j] += f[i] * g[j];

    const int stride = gridDim.x * blockDim.x;
    for (int q = blockIdx.x * blockDim.x + threadIdx.x; q < TOTAL_QUADS; q += stride) {
        const int r  = q / QUADS_PER_ROW;           // row 0..31
        const int t0 = (q - r * QUADS_PER_ROW) * 4; // output offset in row, %4==0

        const float* xp = x + (long long)r * T_IN + t0;  // 16B-aligned
        const float4 v0 = *reinterpret_cast<const float4*>(xp);
        const float4 v1 = *reinterpret_cast<const float4*>(xp + 4);
        const float4 v2 = *reinterpret_cast<const float4*>(xp + 8);
        const float4 v3 = *reinterpret_cast<const float4*>(xp + 12);

        float a[16] = {v0.x, v0.y, v0.z, v0.w,
                       v1.x, v1.y, v1.z, v1.w,
                       v2.x, v2.y, v2.z, v2.w,
                       v3.x, v3.y, v3.z, v3.w};

        float o[4];
#pragma unroll
        for (int j = 0; j < 4; ++j) {
            float s = 0.0f;
#pragma unroll
            for (int k = 0; k < 13; ++k) s = fmaf(c[k], a[j + k], s);
            o[j] = s;
        }

        *reinterpret_cast<float4*>(out + (long long)r * T_OUT + t0) =
            make_float4(o[0], o[1], o[2], o[3]);
    }
}

extern "C" void kernel_launch(void* const* d_in, const int* in_sizes, int n_in,
                              void* d_out, int out_size, void* d_ws, size_t ws_size,
                              hipStream_t stream) {
    const float* x  = (const float*)d_in[0];
    const float* fd = (const float*)d_in[1];
    const float* gs = (const float*)d_in[2];
    float* out = (float*)d_out;

    // 8192 blocks x 256 threads -> 4 quads per thread (grid-stride),
    // amortizes the 45-FMA coefficient composition.
    pinn_fused_conv13<<<8192, 256, 0, stream>>>(x, fd, gs, out);
}